// Round 15
// baseline (217.214 us; speedup 1.0000x reference)
//
#include <hip/hip_runtime.h>
#include <hip/hip_bf16.h>

// B=2, H=96, W=128, D=64, C=32, F=32, kernel 3x3x3, pad 1 in h/w, depth-shifted.
#define Bn 2
#define Hn 96
#define Wn 128
#define Dn 64
#define Cn 32
#define Fn 32
#define TH 2                 // patch: 2 h-rows
#define TW 8                 // patch: 8 w-cols  -> 16 pixels, one per wave
#define CW (TW + 2)          // 10 staged w-cols
#define NCOLS (4 * CW)       // 40 cols x 4KB bf16 = 160KB LDS
#define COLSZ (Dn * Cn)      // 2048 shorts per column

typedef short bf16x8 __attribute__((ext_vector_type(8)));
typedef float f32x4  __attribute__((ext_vector_type(4)));

__device__ __forceinline__ ushort f2bf(float x) {
    __hip_bfloat16 h = __float2bfloat16(x);   // RNE
    return *reinterpret_cast<ushort*>(&h);
}
// HW packed fp32->bf16 (RNE)
__device__ __forceinline__ uint2 f4bf(float4 v) {
    uint2 r;
    asm("v_cvt_pk_bf16_f32 %0, %1, %2" : "=v"(r.x) : "v"(v.x), "v"(v.y));
    asm("v_cvt_pk_bf16_f32 %0, %1, %2" : "=v"(r.y) : "v"(v.z), "v"(v.w));
    return r;
}

// Rows are 32 shorts (64B) = 4 slots of 16B. slot' = slot ^ ((r>>1)&3):
// 16 consecutive rows at one slot spread over all 8 bank-quads (2-way = free).
// XOR term invariant under row += 16 -> fragment offsets step by +-512 shorts.
__device__ __forceinline__ int swz_off(int r, int slot) {
    return r * 32 + ((slot ^ ((r >> 1) & 3)) << 3);
}

// ---- prep: kT[30][f][c] bf16; taps 0..26 = transpose of kern, taps 27..29 = 0
__global__ void prep_kT(const float* __restrict__ kern, ushort* __restrict__ kT) {
    const int e = blockIdx.x * 256 + threadIdx.x;    // 30*1024 = 30720
    if (e >= 30 * Cn * Fn) return;
    const int c  = e & 31;
    const int f  = (e >> 5) & 31;
    const int kk = e >> 10;
    kT[e] = (kk < 27) ? f2bf(kern[kk * (Cn * Fn) + c * Fn + f]) : (ushort)0;
}

__global__ __launch_bounds__(1024, 4) void sconv3d_mfma(
    const float*  __restrict__ img,   // [B,H,W,D,C]
    const int*    __restrict__ bp,    // [B,H,W]
    const float*  __restrict__ kern,  // [3,3,3,C,F] (fp32, dv path only)
    const ushort* __restrict__ kT,    // [30][F][C] bf16
    const float*  __restrict__ dvp,
    float*        __restrict__ out)   // [B,H,W,D,F]
{
    __shared__ ushort colS[NCOLS * COLSZ];           // 163840 B

    // XCD-chunked, ht-fastest ordering (1536 % 8 == 0 -> bijective)
    const int xcd = blockIdx.x & 7;
    const int i   = blockIdx.x >> 3;
    const int ht  = i % (Hn / TH);
    const int q   = i / (Hn / TH);
    const int cI  = xcd * 4 + q;
    const int wt  = cI & 15;
    const int b   = cI >> 4;
    const int h0  = ht * TH;
    const int w0  = wt * TW;

    const int tid  = threadIdx.x;
    const int lane = tid & 63;
    const int wave = tid >> 6;                       // 0..15
    const int ph   = wave >> 3;
    const int pw   = wave & 7;
    const int h    = h0 + ph;
    const int w    = w0 + pw;

    const int lrow = lane & 15;                      // A row (d in 16) / B f-col
    const int lgrp = lane >> 4;                      // 16B k-slot (c-block)

    const float dv  = *dvp;
    const int   bpc = bp[(b * Hn + h) * Wn + w];

    // ---- per-wave tap shifts & validity
    int  sh9[9];
    bool tv[9];
    int  kkb9[9];
#pragma unroll
    for (int kh = 0; kh < 3; ++kh)
#pragma unroll
        for (int kw = 0; kw < 3; ++kw) {
            const int t  = kh * 3 + kw;
            const int hh = h - 1 + kh;
            const int ww = w - 1 + kw;
            const bool v = (hh >= 0) && (hh < Hn) && (ww >= 0) && (ww < Wn);
            tv[t]   = v;
            sh9[t]  = v ? (bpc - bp[(b * Hn + hh) * Wn + ww]) : 0;
            kkb9[t] = v ? t * 3 : 27;                // zero-weight tap if invalid
        }
    const int cbase = (ph * CW + pw) * COLSZ;

    // ---- stage all 40 halo columns (fp32 -> bf16 via cvt_pk, swizzled).
    // Thread handles cols j = 2*it + jbase; (2*it)/10 and (2*it)%10 are LITERALS.
    {
        const int jbase = tid >> 9;                  // 0 or 1
        const int sl    = tid & 511;
        const int swzT  = swz_off(sl >> 3, (sl >> 1) & 3) + (sl & 1) * 4;
        const bool wl_ok = !((w0 == 0) && (jbase == 0));        // cc==0 boundary
        const bool wr_ok = !((w0 == Wn - TW) && (jbase == 1));  // cc==8 boundary
        const float*  gbase = img + (size_t)((b * Hn + (h0 - 1)) * Wn + (w0 - 1) + jbase) * COLSZ + sl * 4;
        ushort*       lbase = colS + jbase * COLSZ + swzT;
#pragma unroll
        for (int it = 0; it < 20; ++it) {
            const int r  = (2 * it) / 10;            // literal 0..3
            const int cc = (2 * it) % 10;            // literal 0,2,4,6,8
            const int hh = h0 - 1 + r;
            const bool v = (hh >= 0) && (hh < Hn) &&
                           (cc == 0 ? wl_ok : (cc == 8 ? wr_ok : true));
            float4 x = make_float4(0.f, 0.f, 0.f, 0.f);
            if (v) x = *(const float4*)(gbase + (size_t)(r * Wn + cc) * COLSZ);
            const uint2 u = f4bf(x);
            *(uint2*)(lbase + 2 * it * COLSZ) = u;
        }
    }
    __syncthreads();   // the ONLY barrier

    f32x4 acc[4][2];
#pragma unroll
    for (int i2 = 0; i2 < 4; ++i2)
#pragma unroll
        for (int j2 = 0; j2 < 2; ++j2) acc[i2][j2] = (f32x4)0.f;

    // ---- 3-deep software-pipelined compute, issue order pinned by T19 SGB.
    // Stage st: fix Aq[st%3] validity, prefetch stage st+2 (4 ds_read + 2 kT),
    // 8 MFMAs on Aq/Bq[st%3]. Pins keep loads 2 stages ahead of their MFMAs.
    bf16x8 Aq[3][4];
    bf16x8 Bq[3][2];

#define STAGE_LOAD(BUF, G, KD)                                                   \
    {                                                                            \
        const int i1_ = lrow + 15 + sh9[G] + (KD);                               \
        const int o1_ = i1_ * 32 + ((lgrp ^ ((i1_ >> 1) & 3)) << 3);             \
        const bool v0_ = (i1_ >= 16), v3_ = (i1_ <= 31);                         \
        const ushort* cp_ = colS + cbase + (((G) / 3) * CW + ((G) % 3)) * COLSZ; \
        Aq[BUF][0] = *(const bf16x8*)&cp_[v0_ ? o1_ - 512 : o1_];                \
        Aq[BUF][1] = *(const bf16x8*)&cp_[o1_];                                  \
        Aq[BUF][2] = *(const bf16x8*)&cp_[o1_ + 512];                            \
        Aq[BUF][3] = *(const bf16x8*)&cp_[v3_ ? o1_ + 1024 : o1_];               \
        Bq[BUF][0] = *(const bf16x8*)&kT[((kkb9[G] + (KD)) * Fn + lrow) * Cn + lgrp * 8];      \
        Bq[BUF][1] = *(const bf16x8*)&kT[((kkb9[G] + (KD)) * Fn + lrow + 16) * Cn + lgrp * 8]; \
    }

    STAGE_LOAD(0, 0, 0)                               // prologue: stages 0,1
    STAGE_LOAD(1, 0, 1)

#pragma unroll
    for (int st = 0; st < 27; ++st) {
        const int cur = st % 3;                       // literal under unroll
        const int g = st / 3, kd = st % 3;
        // validity fix (zero OOB-depth fragments; reads landed 2 stages ago)
        {
            const int i1f = lrow + 15 + sh9[g] + kd;
            Aq[cur][0] = (i1f >= 16) ? Aq[cur][0] : (bf16x8)0;
            Aq[cur][3] = (i1f <= 31) ? Aq[cur][3] : (bf16x8)0;
        }
        if (st < 25) {
            STAGE_LOAD(((st + 2) % 3), ((st + 2) / 3), ((st + 2) % 3))
        }
        __builtin_amdgcn_s_setprio(1);
        acc[0][0] = __builtin_amdgcn_mfma_f32_16x16x32_bf16(Aq[cur][0], Bq[cur][0], acc[0][0], 0, 0, 0);
        acc[0][1] = __builtin_amdgcn_mfma_f32_16x16x32_bf16(Aq[cur][0], Bq[cur][1], acc[0][1], 0, 0, 0);
        acc[1][0] = __builtin_amdgcn_mfma_f32_16x16x32_bf16(Aq[cur][1], Bq[cur][0], acc[1][0], 0, 0, 0);
        acc[1][1] = __builtin_amdgcn_mfma_f32_16x16x32_bf16(Aq[cur][1], Bq[cur][1], acc[1][1], 0, 0, 0);
        acc[2][0] = __builtin_amdgcn_mfma_f32_16x16x32_bf16(Aq[cur][2], Bq[cur][0], acc[2][0], 0, 0, 0);
        acc[2][1] = __builtin_amdgcn_mfma_f32_16x16x32_bf16(Aq[cur][2], Bq[cur][1], acc[2][1], 0, 0, 0);
        acc[3][0] = __builtin_amdgcn_mfma_f32_16x16x32_bf16(Aq[cur][3], Bq[cur][0], acc[3][0], 0, 0, 0);
        acc[3][1] = __builtin_amdgcn_mfma_f32_16x16x32_bf16(Aq[cur][3], Bq[cur][1], acc[3][1], 0, 0, 0);
        __builtin_amdgcn_s_setprio(0);
        // T19 pins: this stage's region must emit {4 ds_read, 2 vmem_read, 8 mfma}
        if (st < 25) {
            __builtin_amdgcn_sched_group_barrier(0x100, 4, 0);  // DS_READ
            __builtin_amdgcn_sched_group_barrier(0x020, 2, 0);  // VMEM_READ
        }
        __builtin_amdgcn_sched_group_barrier(0x008, 8, 0);      // MFMA
    }
#undef STAGE_LOAD

    // ---- dv != 0 correction (dead for this benchmark; keeps semantics general)
    if (dv != 0.0f) {
#pragma unroll
        for (int kh = 0; kh < 3; ++kh)
#pragma unroll
            for (int kw = 0; kw < 3; ++kw) {
                const bool sp = tv[kh * 3 + kw];
                const int  s  = sh9[kh * 3 + kw];
                for (int kd = 0; kd < 3; ++kd) {
                    float ks0 = 0.f, ks1 = 0.f;
                    for (int c = 0; c < Cn; ++c) {
                        const float* kp = kern + (size_t)(((kh * 3 + kw) * 3 + kd) * Cn + c) * Fn;
                        ks0 += kp[lrow];
                        ks1 += kp[16 + lrow];
                    }
                    for (int dt = 0; dt < 4; ++dt)
                        for (int j = 0; j < 4; ++j) {
                            const int d   = dt * 16 + lgrp * 4 + j;
                            const int idx = d + s + kd - 1;
                            const bool valid = sp && (idx >= 0) && (idx < Dn);
                            if (!valid) { acc[dt][0][j] += dv * ks0; acc[dt][1][j] += dv * ks1; }
                        }
                }
            }
    }

    // ---- epilogue: D lane l reg j -> d = dt*16 + lgrp*4 + j, f = ft*16 + lrow
    const size_t pixbase = ((size_t)(b * Hn + h) * Wn + w) * (Dn * Fn);
#pragma unroll
    for (int dt = 0; dt < 4; ++dt)
#pragma unroll
        for (int ft = 0; ft < 2; ++ft)
#pragma unroll
            for (int j = 0; j < 4; ++j) {
                const int d = dt * 16 + lgrp * 4 + j;
                const int f = ft * 16 + lrow;
                out[pixbase + d * Fn + f] = acc[dt][ft][j];
            }
}

extern "C" void kernel_launch(void* const* d_in, const int* in_sizes, int n_in,
                              void* d_out, int out_size, void* d_ws, size_t ws_size,
                              hipStream_t stream) {
    const float* img  = (const float*)d_in[0];
    const int*   bp   = (const int*)d_in[1];
    const float* kern = (const float*)d_in[2];
    const float* dvp  = (const float*)d_in[3];
    float* out = (float*)d_out;
    ushort* kT = (ushort*)d_ws;                      // 30*32*32*2 = 61440 B

    hipLaunchKernelGGL(prep_kT, dim3(120), dim3(256), 0, stream, kern, kT);

    const int nblk = Bn * (Hn / TH) * (Wn / TW);     // 1536
    hipLaunchKernelGGL(sconv3d_mfma, dim3(nblk), dim3(1024), 0, stream,
                       img, bp, kern, kT, dvp, out);
}

// Round 16
// 216.184 us; speedup vs baseline: 1.0048x; 1.0048x over previous
//
#include <hip/hip_runtime.h>
#include <hip/hip_bf16.h>

// B=2, H=96, W=128, D=64, C=32, F=32, kernel 3x3x3, pad 1 in h/w, depth-shifted.
#define Bn 2
#define Hn 96
#define Wn 128
#define Dn 64
#define Cn 32
#define Fn 32
#define TH 2                 // patch: 2 h-rows
#define TW 8                 // patch: 8 w-cols  -> 16 pixels, one per wave
#define CW (TW + 2)          // 10 staged w-cols
#define NCOLS (4 * CW)       // 40 cols x 4KB bf16 = 160KB LDS
#define COLSZ (Dn * Cn)      // 2048 shorts per column

typedef short bf16x8 __attribute__((ext_vector_type(8)));
typedef float f32x4  __attribute__((ext_vector_type(4)));

__device__ __forceinline__ ushort f2bf(float x) {
    __hip_bfloat16 h = __float2bfloat16(x);   // RNE
    return *reinterpret_cast<ushort*>(&h);
}
// HW packed fp32->bf16 (RNE)
__device__ __forceinline__ uint2 f4bf(float4 v) {
    uint2 r;
    asm("v_cvt_pk_bf16_f32 %0, %1, %2" : "=v"(r.x) : "v"(v.x), "v"(v.y));
    asm("v_cvt_pk_bf16_f32 %0, %1, %2" : "=v"(r.y) : "v"(v.z), "v"(v.w));
    return r;
}

// Rows are 32 shorts (64B) = 4 slots of 16B. slot' = slot ^ ((r>>1)&3):
// 16 consecutive rows at one slot spread over all 8 bank-quads (2-way = free).
// XOR term invariant under row += 16 -> fragment offsets step by +-512 shorts.
__device__ __forceinline__ int swz_off(int r, int slot) {
    return r * 32 + ((slot ^ ((r >> 1) & 3)) << 3);
}

// ---- prep: kT[30][f][c] bf16; taps 0..26 = transpose of kern, taps 27..29 = 0
__global__ void prep_kT(const float* __restrict__ kern, ushort* __restrict__ kT) {
    const int e = blockIdx.x * 256 + threadIdx.x;    // 30*1024 = 30720
    if (e >= 30 * Cn * Fn) return;
    const int c  = e & 31;
    const int f  = (e >> 5) & 31;
    const int kk = e >> 10;
    kT[e] = (kk < 27) ? f2bf(kern[kk * (Cn * Fn) + c * Fn + f]) : (ushort)0;
}

// waves_per_eu(4,4): occupancy is LDS-bound at 4 waves/EU anyway; pin the
// register allocator to the SAME target so its budget is 128 VGPR, not the
// default 64 (r13-r15: 64-reg squeeze coalesced or spilled every pipeline).
__global__ __launch_bounds__(1024)
__attribute__((amdgpu_waves_per_eu(4, 4)))
void sconv3d_mfma(
    const float*  __restrict__ img,   // [B,H,W,D,C]
    const int*    __restrict__ bp,    // [B,H,W]
    const float*  __restrict__ kern,  // [3,3,3,C,F] (fp32, dv path only)
    const ushort* __restrict__ kT,    // [30][F][C] bf16
    const float*  __restrict__ dvp,
    float*        __restrict__ out)   // [B,H,W,D,F]
{
    __shared__ ushort colS[NCOLS * COLSZ];           // 163840 B

    // XCD-chunked, ht-fastest ordering (1536 % 8 == 0 -> bijective)
    const int xcd = blockIdx.x & 7;
    const int i   = blockIdx.x >> 3;
    const int ht  = i % (Hn / TH);
    const int q   = i / (Hn / TH);
    const int cI  = xcd * 4 + q;
    const int wt  = cI & 15;
    const int b   = cI >> 4;
    const int h0  = ht * TH;
    const int w0  = wt * TW;

    const int tid  = threadIdx.x;
    const int lane = tid & 63;
    const int wave = tid >> 6;                       // 0..15
    const int ph   = wave >> 3;
    const int pw   = wave & 7;
    const int h    = h0 + ph;
    const int w    = w0 + pw;

    const int lrow = lane & 15;                      // A row (d in 16) / B f-col
    const int lgrp = lane >> 4;                      // 16B k-slot (c-block)

    const float dv  = *dvp;
    const int   bpc = bp[(b * Hn + h) * Wn + w];

    // ---- per-wave tap shifts & validity
    int  sh9[9];
    bool tv[9];
    int  kkb9[9];
#pragma unroll
    for (int kh = 0; kh < 3; ++kh)
#pragma unroll
        for (int kw = 0; kw < 3; ++kw) {
            const int t  = kh * 3 + kw;
            const int hh = h - 1 + kh;
            const int ww = w - 1 + kw;
            const bool v = (hh >= 0) && (hh < Hn) && (ww >= 0) && (ww < Wn);
            tv[t]   = v;
            sh9[t]  = v ? (bpc - bp[(b * Hn + hh) * Wn + ww]) : 0;
            kkb9[t] = v ? t * 3 : 27;                // zero-weight tap if invalid
        }
    const int cbase = (ph * CW + pw) * COLSZ;

    // ---- stage all 40 halo columns (fp32 -> bf16 via cvt_pk, swizzled).
    // Thread handles cols j = 2*it + jbase; (2*it)/10 and (2*it)%10 are LITERALS.
    {
        const int jbase = tid >> 9;                  // 0 or 1
        const int sl    = tid & 511;
        const int swzT  = swz_off(sl >> 3, (sl >> 1) & 3) + (sl & 1) * 4;
        const bool wl_ok = !((w0 == 0) && (jbase == 0));        // cc==0 boundary
        const bool wr_ok = !((w0 == Wn - TW) && (jbase == 1));  // cc==8 boundary
        const float*  gbase = img + (size_t)((b * Hn + (h0 - 1)) * Wn + (w0 - 1) + jbase) * COLSZ + sl * 4;
        ushort*       lbase = colS + jbase * COLSZ + swzT;
#pragma unroll
        for (int it = 0; it < 20; ++it) {
            const int r  = (2 * it) / 10;            // literal 0..3
            const int cc = (2 * it) % 10;            // literal 0,2,4,6,8
            const int hh = h0 - 1 + r;
            const bool v = (hh >= 0) && (hh < Hn) &&
                           (cc == 0 ? wl_ok : (cc == 8 ? wr_ok : true));
            float4 x = make_float4(0.f, 0.f, 0.f, 0.f);
            if (v) x = *(const float4*)(gbase + (size_t)(r * Wn + cc) * COLSZ);
            const uint2 u = f4bf(x);
            *(uint2*)(lbase + 2 * it * COLSZ) = u;
        }
    }
    __syncthreads();   // the ONLY barrier

    f32x4 acc[4][2];
#pragma unroll
    for (int i2 = 0; i2 < 4; ++i2)
#pragma unroll
        for (int j2 = 0; j2 < 2; ++j2) acc[i2][j2] = (f32x4)0.f;

    // ---- 3-deep software-pipelined compute, issue order pinned by T19 SGB.
    // Stage st: fix Aq[st%3] validity, prefetch stage st+2 (4 ds_read + 2 kT),
    // 8 MFMAs on Aq/Bq[st%3]. Pins keep loads 2 stages ahead of their MFMAs.
    bf16x8 Aq[3][4];
    bf16x8 Bq[3][2];

#define STAGE_LOAD(BUF, G, KD)                                                   \
    {                                                                            \
        const int i1_ = lrow + 15 + sh9[G] + (KD);                               \
        const int o1_ = i1_ * 32 + ((lgrp ^ ((i1_ >> 1) & 3)) << 3);             \
        const bool v0_ = (i1_ >= 16), v3_ = (i1_ <= 31);                         \
        const ushort* cp_ = colS + cbase + (((G) / 3) * CW + ((G) % 3)) * COLSZ; \
        Aq[BUF][0] = *(const bf16x8*)&cp_[v0_ ? o1_ - 512 : o1_];                \
        Aq[BUF][1] = *(const bf16x8*)&cp_[o1_];                                  \
        Aq[BUF][2] = *(const bf16x8*)&cp_[o1_ + 512];                            \
        Aq[BUF][3] = *(const bf16x8*)&cp_[v3_ ? o1_ + 1024 : o1_];               \
        Bq[BUF][0] = *(const bf16x8*)&kT[((kkb9[G] + (KD)) * Fn + lrow) * Cn + lgrp * 8];      \
        Bq[BUF][1] = *(const bf16x8*)&kT[((kkb9[G] + (KD)) * Fn + lrow + 16) * Cn + lgrp * 8]; \
    }

    STAGE_LOAD(0, 0, 0)                               // prologue: stages 0,1
    STAGE_LOAD(1, 0, 1)

#pragma unroll
    for (int st = 0; st < 27; ++st) {
        const int cur = st % 3;                       // literal under unroll
        const int g = st / 3, kd = st % 3;
        // validity fix (zero OOB-depth fragments; reads landed 2 stages ago)
        {
            const int i1f = lrow + 15 + sh9[g] + kd;
            Aq[cur][0] = (i1f >= 16) ? Aq[cur][0] : (bf16x8)0;
            Aq[cur][3] = (i1f <= 31) ? Aq[cur][3] : (bf16x8)0;
        }
        if (st < 25) {
            STAGE_LOAD(((st + 2) % 3), ((st + 2) / 3), ((st + 2) % 3))
        }
        __builtin_amdgcn_s_setprio(1);
        acc[0][0] = __builtin_amdgcn_mfma_f32_16x16x32_bf16(Aq[cur][0], Bq[cur][0], acc[0][0], 0, 0, 0);
        acc[0][1] = __builtin_amdgcn_mfma_f32_16x16x32_bf16(Aq[cur][0], Bq[cur][1], acc[0][1], 0, 0, 0);
        acc[1][0] = __builtin_amdgcn_mfma_f32_16x16x32_bf16(Aq[cur][1], Bq[cur][0], acc[1][0], 0, 0, 0);
        acc[1][1] = __builtin_amdgcn_mfma_f32_16x16x32_bf16(Aq[cur][1], Bq[cur][1], acc[1][1], 0, 0, 0);
        acc[2][0] = __builtin_amdgcn_mfma_f32_16x16x32_bf16(Aq[cur][2], Bq[cur][0], acc[2][0], 0, 0, 0);
        acc[2][1] = __builtin_amdgcn_mfma_f32_16x16x32_bf16(Aq[cur][2], Bq[cur][1], acc[2][1], 0, 0, 0);
        acc[3][0] = __builtin_amdgcn_mfma_f32_16x16x32_bf16(Aq[cur][3], Bq[cur][0], acc[3][0], 0, 0, 0);
        acc[3][1] = __builtin_amdgcn_mfma_f32_16x16x32_bf16(Aq[cur][3], Bq[cur][1], acc[3][1], 0, 0, 0);
        __builtin_amdgcn_s_setprio(0);
        // T19 pins: this stage's region must emit {4 ds_read, 2 vmem_read, 8 mfma}
        if (st < 25) {
            __builtin_amdgcn_sched_group_barrier(0x100, 4, 0);  // DS_READ
            __builtin_amdgcn_sched_group_barrier(0x020, 2, 0);  // VMEM_READ
        }
        __builtin_amdgcn_sched_group_barrier(0x008, 8, 0);      // MFMA
    }
#undef STAGE_LOAD

    // ---- dv != 0 correction (dead for this benchmark; keeps semantics general)
    if (dv != 0.0f) {
#pragma unroll
        for (int kh = 0; kh < 3; ++kh)
#pragma unroll
            for (int kw = 0; kw < 3; ++kw) {
                const bool sp = tv[kh * 3 + kw];
                const int  s  = sh9[kh * 3 + kw];
                for (int kd = 0; kd < 3; ++kd) {
                    float ks0 = 0.f, ks1 = 0.f;
                    for (int c = 0; c < Cn; ++c) {
                        const float* kp = kern + (size_t)(((kh * 3 + kw) * 3 + kd) * Cn + c) * Fn;
                        ks0 += kp[lrow];
                        ks1 += kp[16 + lrow];
                    }
                    for (int dt = 0; dt < 4; ++dt)
                        for (int j = 0; j < 4; ++j) {
                            const int d   = dt * 16 + lgrp * 4 + j;
                            const int idx = d + s + kd - 1;
                            const bool valid = sp && (idx >= 0) && (idx < Dn);
                            if (!valid) { acc[dt][0][j] += dv * ks0; acc[dt][1][j] += dv * ks1; }
                        }
                }
            }
    }

    // ---- epilogue: D lane l reg j -> d = dt*16 + lgrp*4 + j, f = ft*16 + lrow
    const size_t pixbase = ((size_t)(b * Hn + h) * Wn + w) * (Dn * Fn);
#pragma unroll
    for (int dt = 0; dt < 4; ++dt)
#pragma unroll
        for (int ft = 0; ft < 2; ++ft)
#pragma unroll
            for (int j = 0; j < 4; ++j) {
                const int d = dt * 16 + lgrp * 4 + j;
                const int f = ft * 16 + lrow;
                out[pixbase + d * Fn + f] = acc[dt][ft][j];
            }
}

extern "C" void kernel_launch(void* const* d_in, const int* in_sizes, int n_in,
                              void* d_out, int out_size, void* d_ws, size_t ws_size,
                              hipStream_t stream) {
    const float* img  = (const float*)d_in[0];
    const int*   bp   = (const int*)d_in[1];
    const float* kern = (const float*)d_in[2];
    const float* dvp  = (const float*)d_in[3];
    float* out = (float*)d_out;
    ushort* kT = (ushort*)d_ws;                      // 30*32*32*2 = 61440 B

    hipLaunchKernelGGL(prep_kT, dim3(120), dim3(256), 0, stream, kern, kT);

    const int nblk = Bn * (Hn / TH) * (Wn / TW);     // 1536
    hipLaunchKernelGGL(sconv3d_mfma, dim3(nblk), dim3(1024), 0, stream,
                       img, bp, kern, kT, dvp, out);
}

// Round 17
// 174.468 us; speedup vs baseline: 1.2450x; 1.2391x over previous
//
#include <hip/hip_runtime.h>
#include <hip/hip_bf16.h>

// B=2, H=96, W=128, D=64, C=32, F=32, kernel 3x3x3, pad 1 in h/w, depth-shifted.
// r12 configuration — session best (177 us). Verified plateau:
//  - 2x8 pixel patch per 1024-thread block, 40 halo columns in 160KB LDS
//  - bf16 staging via v_cvt_pk_bf16_f32, literal stage addressing, XOR swizzle
//  - branchless 27-tap MFMA stream (zero-weight tap 27 for invalid taps)
//  - XCD-chunked ht-fastest block order (bijective, 1536 % 8 == 0)
// Escape attempts that failed (r13-r16): split cvt+global_load_lds (+16 us net),
// explicit 2/3-deep pipelines (coalesced or spilled at the 64-VGPR regalloc
// squeeze), sched_group_barrier pins (spill), amdgpu_waves_per_eu (ignored).
#define Bn 2
#define Hn 96
#define Wn 128
#define Dn 64
#define Cn 32
#define Fn 32
#define TH 2                 // patch: 2 h-rows
#define TW 8                 // patch: 8 w-cols  -> 16 pixels, one per wave
#define CW (TW + 2)          // 10 staged w-cols
#define NCOLS (4 * CW)       // 4 h-rows x 10 w-cols = 40 cols x 4KB = 160KB LDS
#define COLSZ (Dn * Cn)      // 2048 shorts per column

typedef short bf16x8 __attribute__((ext_vector_type(8)));
typedef float f32x4  __attribute__((ext_vector_type(4)));

__device__ __forceinline__ ushort f2bf(float x) {
    __hip_bfloat16 h = __float2bfloat16(x);   // RNE (prep kernel only)
    return *reinterpret_cast<ushort*>(&h);
}

// HW packed fp32->bf16 (RNE): 2 insts per float4 vs ~20 for the software path.
__device__ __forceinline__ uint2 f4bf(float4 v) {
    uint2 r;
    asm("v_cvt_pk_bf16_f32 %0, %1, %2" : "=v"(r.x) : "v"(v.x), "v"(v.y));
    asm("v_cvt_pk_bf16_f32 %0, %1, %2" : "=v"(r.y) : "v"(v.z), "v"(v.w));
    return r;
}

// Rows are 32 shorts (64B) = 4 slots of 16B. slot' = slot ^ ((r>>1)&3):
// 16 consecutive rows at one slot spread over all 8 bank-quads (2-way = free).
// XOR term invariant under row += 16 -> fragment offsets step by +-512 shorts.
__device__ __forceinline__ int swz_off(int r, int slot) {
    return r * 32 + ((slot ^ ((r >> 1) & 3)) << 3);
}

// ---- prep: kT[30][f][c] bf16; taps 0..26 = transpose of kern, taps 27..29 = 0
__global__ void prep_kT(const float* __restrict__ kern, ushort* __restrict__ kT) {
    const int e = blockIdx.x * 256 + threadIdx.x;    // 30*1024 = 30720
    if (e >= 30 * Cn * Fn) return;
    const int c  = e & 31;
    const int f  = (e >> 5) & 31;
    const int kk = e >> 10;
    kT[e] = (kk < 27) ? f2bf(kern[kk * (Cn * Fn) + c * Fn + f]) : (ushort)0;
}

__global__ __launch_bounds__(1024, 4) void sconv3d_mfma(
    const float*  __restrict__ img,   // [B,H,W,D,C]
    const int*    __restrict__ bp,    // [B,H,W]
    const float*  __restrict__ kern,  // [3,3,3,C,F] (fp32, dv path only)
    const ushort* __restrict__ kT,    // [30][F][C] bf16
    const float*  __restrict__ dvp,
    float*        __restrict__ out)   // [B,H,W,D,F]
{
    // 40 halo columns, bf16 [col][d 0..63][c], swizzled 16B slots.
    __shared__ ushort colS[NCOLS * COLSZ];           // 163840 B

    // XCD-chunked, ht-fastest ordering (1536 % 8 == 0 -> bijective):
    // each XCD owns 4 vertical strips; consecutive blocks share 20/40 halo cols.
    const int xcd = blockIdx.x & 7;
    const int i   = blockIdx.x >> 3;                 // 0..191
    const int ht  = i % (Hn / TH);                   // 0..47, fastest
    const int q   = i / (Hn / TH);                   // 0..3
    const int cI  = xcd * 4 + q;                     // 0..31
    const int wt  = cI & 15;
    const int b   = cI >> 4;
    const int h0  = ht * TH;
    const int w0  = wt * TW;

    const int tid  = threadIdx.x;
    const int lane = tid & 63;
    const int wave = tid >> 6;                       // 0..15
    const int ph   = wave >> 3;                      // 0..1
    const int pw   = wave & 7;                       // 0..7
    const int h    = h0 + ph;
    const int w    = w0 + pw;

    const int lrow = lane & 15;                      // A row (d in 16) / B f-col
    const int lgrp = lane >> 4;                      // 16B k-slot (c-block)

    const float dv  = *dvp;
    const int   bpc = bp[(b * Hn + h) * Wn + w];

    // ---- per-wave tap shifts & validity (latency overlaps staging below)
    int  sh[9];
    bool tv[9];
#pragma unroll
    for (int kh = 0; kh < 3; ++kh)
#pragma unroll
        for (int kw = 0; kw < 3; ++kw) {
            const int hh = h - 1 + kh;
            const int ww = w - 1 + kw;
            const bool v = (hh >= 0) && (hh < Hn) && (ww >= 0) && (ww < Wn);
            tv[kh * 3 + kw] = v;
            sh[kh * 3 + kw] = v ? (bpc - bp[(b * Hn + hh) * Wn + ww]) : 0;
        }

    // ---- stage all 40 halo columns (fp32 -> bf16 via cvt_pk, swizzled).
    // Thread handles cols j = 2*it + jbase; (2*it)/10 and (2*it)%10 are LITERALS
    // (2*it even => +jbase never carries into the quotient). No div/mod at runtime.
    {
        const int jbase = tid >> 9;                  // 0 or 1
        const int sl    = tid & 511;
        const int swzT  = swz_off(sl >> 3, (sl >> 1) & 3) + (sl & 1) * 4;  // shorts
        const bool wl_ok = !((w0 == 0) && (jbase == 0));        // cc==0 boundary
        const bool wr_ok = !((w0 == Wn - TW) && (jbase == 1));  // cc==8 boundary
        const float*  gbase = img + (size_t)((b * Hn + (h0 - 1)) * Wn + (w0 - 1) + jbase) * COLSZ + sl * 4;
        ushort*       lbase = colS + jbase * COLSZ + swzT;
#pragma unroll
        for (int it = 0; it < 20; ++it) {
            const int r  = (2 * it) / 10;            // literal 0..3
            const int cc = (2 * it) % 10;            // literal 0,2,4,6,8
            const int hh = h0 - 1 + r;
            const bool v = (hh >= 0) && (hh < Hn) &&
                           (cc == 0 ? wl_ok : (cc == 8 ? wr_ok : true));
            float4 x = make_float4(0.f, 0.f, 0.f, 0.f);
            if (v) x = *(const float4*)(gbase + (size_t)(r * Wn + cc) * COLSZ);
            const uint2 u = f4bf(x);
            *(uint2*)(lbase + 2 * it * COLSZ) = u;
        }
    }
    __syncthreads();   // the ONLY barrier

    f32x4 acc[4][2];
#pragma unroll
    for (int i2 = 0; i2 < 4; ++i2)
#pragma unroll
        for (int j2 = 0; j2 < 2; ++j2) acc[i2][j2] = (f32x4)0.f;

    // ---- branchless straight-line compute: 9 tap groups, 216 MFMA per wave.
    // Invalid taps read the ZERO tap (27) of kT -> B = 0, contribution = 0.
#pragma unroll
    for (int kh = 0; kh < 3; ++kh) {
#pragma unroll
        for (int kw = 0; kw < 3; ++kw) {
            const int t    = kh * 3 + kw;
            const int s    = sh[t];
            const int kkb  = tv[t] ? t * 3 : 27;     // zero-weight tap if invalid
            const ushort* colp = &colS[((ph + kh) * CW + (pw + kw)) * COLSZ];
            bf16x8 bfr[3][2];
#pragma unroll
            for (int kd = 0; kd < 3; ++kd) {
                bfr[kd][0] = *(const bf16x8*)&kT[((kkb + kd) * Fn + lrow)      * Cn + lgrp * 8];
                bfr[kd][1] = *(const bf16x8*)&kT[((kkb + kd) * Fn + lrow + 16) * Cn + lgrp * 8];
            }
            __builtin_amdgcn_s_setprio(1);
#pragma unroll
            for (int kd = 0; kd < 3; ++kd) {
                const int i1 = 16 + lrow + s + kd - 1;   // in [0,47] (|s|<=15)
                const int o1 = swz_off(i1, lgrp);
                // dt=1, dt=2: always depth-valid, unconditional
                const bf16x8 a1 = *(const bf16x8*)&colp[o1];
                acc[1][0] = __builtin_amdgcn_mfma_f32_16x16x32_bf16(a1, bfr[kd][0], acc[1][0], 0, 0, 0);
                acc[1][1] = __builtin_amdgcn_mfma_f32_16x16x32_bf16(a1, bfr[kd][1], acc[1][1], 0, 0, 0);
                const bf16x8 a2 = *(const bf16x8*)&colp[o1 + 512];
                acc[2][0] = __builtin_amdgcn_mfma_f32_16x16x32_bf16(a2, bfr[kd][0], acc[2][0], 0, 0, 0);
                acc[2][1] = __builtin_amdgcn_mfma_f32_16x16x32_bf16(a2, bfr[kd][1], acc[2][1], 0, 0, 0);
                // dt=0: valid iff i1>=16
                {
                    const bool vv = (i1 >= 16);
                    bf16x8 a0 = *(const bf16x8*)&colp[vv ? o1 - 512 : o1];
                    if (!vv) a0 = (bf16x8)0;
                    acc[0][0] = __builtin_amdgcn_mfma_f32_16x16x32_bf16(a0, bfr[kd][0], acc[0][0], 0, 0, 0);
                    acc[0][1] = __builtin_amdgcn_mfma_f32_16x16x32_bf16(a0, bfr[kd][1], acc[0][1], 0, 0, 0);
                }
                // dt=3: valid iff i1<=31
                {
                    const bool vv = (i1 <= 31);
                    bf16x8 a3 = *(const bf16x8*)&colp[vv ? o1 + 1024 : o1];
                    if (!vv) a3 = (bf16x8)0;
                    acc[3][0] = __builtin_amdgcn_mfma_f32_16x16x32_bf16(a3, bfr[kd][0], acc[3][0], 0, 0, 0);
                    acc[3][1] = __builtin_amdgcn_mfma_f32_16x16x32_bf16(a3, bfr[kd][1], acc[3][1], 0, 0, 0);
                }
            }
            __builtin_amdgcn_s_setprio(0);
        }
    }

    // ---- dv != 0 correction (dead for this benchmark; keeps semantics general)
    if (dv != 0.0f) {
#pragma unroll
        for (int kh = 0; kh < 3; ++kh)
#pragma unroll
            for (int kw = 0; kw < 3; ++kw) {
                const bool sp = tv[kh * 3 + kw];
                const int  s  = sh[kh * 3 + kw];
                for (int kd = 0; kd < 3; ++kd) {
                    float ks0 = 0.f, ks1 = 0.f;
                    for (int c = 0; c < Cn; ++c) {
                        const float* kp = kern + (size_t)(((kh * 3 + kw) * 3 + kd) * Cn + c) * Fn;
                        ks0 += kp[lrow];
                        ks1 += kp[16 + lrow];
                    }
                    for (int dt = 0; dt < 4; ++dt)
                        for (int j = 0; j < 4; ++j) {
                            const int d   = dt * 16 + lgrp * 4 + j;
                            const int idx = d + s + kd - 1;
                            const bool valid = sp && (idx >= 0) && (idx < Dn);
                            if (!valid) { acc[dt][0][j] += dv * ks0; acc[dt][1][j] += dv * ks1; }
                        }
                }
            }
    }

    // ---- epilogue: D lane l reg j -> d = dt*16 + lgrp*4 + j, f = ft*16 + lrow
    const size_t pixbase = ((size_t)(b * Hn + h) * Wn + w) * (Dn * Fn);
#pragma unroll
    for (int dt = 0; dt < 4; ++dt)
#pragma unroll
        for (int ft = 0; ft < 2; ++ft)
#pragma unroll
            for (int j = 0; j < 4; ++j) {
                const int d = dt * 16 + lgrp * 4 + j;
                const int f = ft * 16 + lrow;
                out[pixbase + d * Fn + f] = acc[dt][ft][j];
            }
}

extern "C" void kernel_launch(void* const* d_in, const int* in_sizes, int n_in,
                              void* d_out, int out_size, void* d_ws, size_t ws_size,
                              hipStream_t stream) {
    const float* img  = (const float*)d_in[0];
    const int*   bp   = (const int*)d_in[1];
    const float* kern = (const float*)d_in[2];
    const float* dvp  = (const float*)d_in[3];
    float* out = (float*)d_out;
    ushort* kT = (ushort*)d_ws;                      // 30*32*32*2 = 61440 B

    hipLaunchKernelGGL(prep_kT, dim3(120), dim3(256), 0, stream, kern, kT);

    const int nblk = Bn * (Hn / TH) * (Wn / TW);     // 2*48*16 = 1536
    hipLaunchKernelGGL(sconv3d_mfma, dim3(nblk), dim3(1024), 0, stream,
                       img, bp, kern, kT, dvp, out);
}